// Round 16
// baseline (807.292 us; speedup 1.0000x reference)
//
#include <hip/hip_runtime.h>
#include <hip/hip_bf16.h>
#include <stdint.h>

#define M_DIM 8192
#define K_DIM 4096
#define N_DIM 11008
#define NWORDS (N_DIM / 8)   // 1376
#define BM 128
#define BN 128
#define BK 64
#define NT (K_DIM / BK)      // 64

typedef _Float16 half8 __attribute__((ext_vector_type(8)));  // 8 x f16 (4 VGPRs)
typedef __fp16 fp16x2 __attribute__((ext_vector_type(2)));
typedef __attribute__((ext_vector_type(4))) float f32x4;

typedef const __attribute__((address_space(1))) uint32_t glb_u32;
typedef __attribute__((address_space(3))) uint32_t lds_u32;
typedef __attribute__((address_space(3))) char lds_char;

__device__ __forceinline__ uint32_t pkh(float lo, float hi) {
  union { fp16x2 h; uint32_t u; } cv;
  cv.h = __builtin_amdgcn_cvt_pkrtz(lo, hi);
  return cv.u;
}

__device__ __forceinline__ float ub(uint32_t v, int b) {
  return (float)((v >> (8 * b)) & 0xFFu);
}

// raw ds_read_b128: RAW ordering enforced ONLY by our counted lgkm waits
__device__ __forceinline__ half8 dsr128(const lds_char* p) {
  half8 r;
  asm volatile("ds_read_b128 %0, %1" : "=v"(r) : "v"(p));
  return r;
}

#define WAITL0 do { asm volatile("s_waitcnt lgkmcnt(0)" ::: "memory"); \
                    __builtin_amdgcn_sched_barrier(0); } while (0)

// ---------------- fused pre-pass: blocks [0,16384) convert x; rest dequant W ----------------
#define XBLK 16384   // (M*K)/(256*8)
__global__ __launch_bounds__(256) void prep(const float* __restrict__ x,
                                            const int* __restrict__ qweight,
                                            const int* __restrict__ qzeros,
                                            const float* __restrict__ scales,
                                            __fp16* __restrict__ xh,
                                            __fp16* __restrict__ wt) {
  if (blockIdx.x < XBLK) {
    const size_t i8 = ((size_t)blockIdx.x * 256 + threadIdx.x) * 8;
    f32x4 v0 = *(const f32x4*)(x + i8);
    f32x4 v1 = *(const f32x4*)(x + i8 + 4);
    uint4 w;
    w.x = pkh(v0[0], v0[1]); w.y = pkh(v0[2], v0[3]);
    w.z = pkh(v1[0], v1[1]); w.w = pkh(v1[2], v1[3]);
    *(uint4*)(xh + i8) = w;
  } else {
    const int b2 = blockIdx.x - XBLK;
    const int c = b2 >> 4;                    // word column 0..1375 (8 n's)
    const int k = (b2 & 15) * 256 + threadIdx.x;
    const uint32_t q = (uint32_t)qweight[(size_t)k * NWORDS + c];
    const int g = k >> 7;                     // G=128
    const uint32_t z = (uint32_t)qzeros[(size_t)g * NWORDS + c];
    const float* sp = scales + (size_t)g * N_DIM + c * 8;
    const f32x4 s0 = *(const f32x4*)sp;
    const f32x4 s1 = *(const f32x4*)(sp + 4);
    #pragma unroll
    for (int j = 0; j < 8; ++j) {
      const int qv = (int)((q >> (4 * j)) & 15u);
      const int zv = (int)((z >> (4 * j)) & 15u);
      const float sj = (j < 4) ? s0[j & 3] : s1[j & 3];
      const float v = (float)(qv - zv) * sj;
      wt[(size_t)(c * 8 + j) * K_DIM + k] = (__fp16)v;   // coalesced over k (lane)
    }
  }
}

// ---------------- main GEMM: m201-faithful 8-phase / 2-K-tile schedule ----------------
// LDS: tile buffer = (ktile&1)*64KB; within: A 256x128B @0, B 256x128B @32768.
// Storage swizzle: (row r, byte c in [0,128)) at r*128 + (c ^ ((r&7)<<4)).
// Unit = 64 rows x 128B = 8KB = 1 load/thread. Per phase: {ds-reads; 2-3 stage
// units; barrier; lgkm(0); setprio; 16 MFMA; setprio; barrier}. Stages obey
// region-retirement order (WAR-safe, verified); vmcnt(2) only at phases 4/8.
__global__ __launch_bounds__(512, 2) void gemm_f16_256(
    const __fp16* __restrict__ xh,        // [M,K] fp16
    const __fp16* __restrict__ wt,        // [N,K] fp16
    float* __restrict__ out) {            // [M,N] fp32
  __shared__ uint4 lds4[8192];            // 128 KiB
  char* lds = (char*)lds4;
  lds_char* L3 = (lds_char*)lds4;

  const int t = threadIdx.x;
  const int lane = t & 63;
  const int wid = t >> 6;        // 0..7
  const int wm = wid >> 2;       // 0..1  (M half)
  const int wn = wid & 3;        // 0..3  (N quarter)

  // XCD-aware bijective swizzle: 1376 blocks = 8 XCD chunks x 172
  const int flat = blockIdx.x;
  const int swz = (flat & 7) * 172 + (flat >> 3);
  const int bm0 = (swz & 31) * 256;   // M fastest within chunk -> B panel L2-resident
  const int bn0 = (swz >> 5) * 256;

  f32x4 acc[8][4];
  #pragma unroll
  for (int i = 0; i < 8; ++i)
    #pragma unroll
    for (int j = 0; j < 4; ++j)
      #pragma unroll
      for (int k = 0; k < 4; ++k) acc[i][j][k] = 0.0f;

  // ---- staging constants. Thread t covers storage byte rb*128 + t*16 of a unit.
  const int sr = t >> 3;                              // storage row within unit
  const int cb = (((t & 7) ^ (sr & 7)) << 4);         // inverse-swizzled source col
  const char* gA = (const char*)xh + (size_t)(bm0 + sr) * (K_DIM * 2) + cb;
  const char* gB = (const char*)wt + (size_t)(bn0 + sr) * (K_DIM * 2) + cb;
  const int ldst = wid * 1024;                        // wave-uniform; HW adds lane*16

  auto SU = [&](int isB, int rb, int ktile) {         // stage one 8KB unit
    const char* g = (isB ? gB : gA) + (size_t)rb * (K_DIM * 2) + (size_t)ktile * 128;
    __builtin_amdgcn_global_load_lds(
        (glb_u32*)g,
        (lds_u32*)(lds + ((ktile & 1) << 16) + (isB ? 32768 : 0) + rb * 128 + ldst),
        16, 0, 0);
  };

  // ---- read-side constants
  const int swr = (lane & 7) << 4;
  const int q16 = (lane >> 4) << 4;
  const int fr = lane & 15;

  half8 b[4][2], a[2][2];

  auto readB8 = [&](const lds_char* B) {   // 8 reads: all b-frags of a K-tile
    #pragma unroll
    for (int ni = 0; ni < 4; ++ni)
      #pragma unroll
      for (int ks = 0; ks < 2; ++ks)
        b[ni][ks] = dsr128(B + ((((ni * 16 + fr) << 7) + ks * 64 + q16) ^ swr));
  };
  auto readA4 = [&](const lds_char* A, int q) {   // 4 reads: quadrant q's a-frags
    #pragma unroll
    for (int m2 = 0; m2 < 2; ++m2)
      #pragma unroll
      for (int ks = 0; ks < 2; ++ks)
        a[m2][ks] = dsr128(A + ((((q * 32 + m2 * 16 + fr) << 7) + ks * 64 + q16) ^ swr));
  };
  auto MM = [&](int base) {                       // 16-MFMA cluster (base literal)
    __builtin_amdgcn_s_setprio(1);
    #pragma unroll
    for (int m2 = 0; m2 < 2; ++m2)
      #pragma unroll
      for (int ni = 0; ni < 4; ++ni)
        #pragma unroll
        for (int ks = 0; ks < 2; ++ks)
          acc[base + m2][ni] = __builtin_amdgcn_mfma_f32_16x16x32_f16(
              a[m2][ks], b[ni][ks], acc[base + m2][ni], 0, 0, 0);
    __builtin_amdgcn_s_setprio(0);
  };

  // prologue: tile0 full (8 units) + tile1 A-u0,A-u2 -> vmcnt(2) leaves those in flight
  SU(1, 0, 0); SU(1, 64, 0); SU(1, 128, 0); SU(1, 192, 0);
  SU(0, 0, 0); SU(0, 64, 0); SU(0, 128, 0); SU(0, 192, 0);
  SU(0, 0, 1); SU(0, 128, 1);
  asm volatile("s_waitcnt vmcnt(2)" ::: "memory");
  __builtin_amdgcn_s_barrier();

  for (int kt = 0; kt < NT; kt += 2) {
    const int k1 = kt + 1, k2 = kt + 2, k3 = kt + 3;
    const lds_char* Ap = L3 + wm * 16384;            // P buffer (even tiles)
    const lds_char* Bp = L3 + 32768 + wn * 8192;
    const lds_char* Aq = L3 + 65536 + wm * 16384;    // Q buffer (odd tiles)
    const lds_char* Bq = L3 + 65536 + 32768 + wn * 8192;
    const bool p2 = (k2 < NT), p3 = (k3 < NT);

    // ---- ph1: q0 of k0; stage k1 B-u0,B-u1,A-u1 (regions retired prev ph5-8)
    readB8(Bp); readA4(Ap, 0);
    SU(1, 0, k1); SU(1, 64, k1); SU(0, 64, k1);
    asm volatile("s_waitcnt lgkmcnt(8)" ::: "memory");
    __builtin_amdgcn_s_barrier(); WAITL0; MM(0); __builtin_amdgcn_s_barrier();

    // ---- ph2: q1; stage k1 B-u2,B-u3,A-u3
    readA4(Ap, 1);
    SU(1, 128, k1); SU(1, 192, k1); SU(0, 192, k1);
    __builtin_amdgcn_s_barrier(); WAITL0; MM(2); __builtin_amdgcn_s_barrier();

    // ---- ph3: q2; stage k2 A-u0,A-u2 (P rows 0-63/128-191 retired at ph2 end)
    readA4(Ap, 2);
    if (p2) { SU(0, 0, k2); SU(0, 128, k2); }
    __builtin_amdgcn_s_barrier(); WAITL0; MM(4); __builtin_amdgcn_s_barrier();

    // ---- ph4: q3; vmcnt(2) proves k1 fully landed (only ph3's pair in flight)
    readA4(Ap, 3);
    __builtin_amdgcn_s_barrier(); WAITL0; MM(6);
    if (p2) asm volatile("s_waitcnt vmcnt(2)" ::: "memory");
    else    asm volatile("s_waitcnt vmcnt(0)" ::: "memory");
    __builtin_amdgcn_s_barrier();

    // ---- ph5: q0 of k1; stage k2 B-u0,B-u1,A-u1 (P-B + A-u1 retired at ph4 end)
    readB8(Bq); readA4(Aq, 0);
    if (p2) { SU(1, 0, k2); SU(1, 64, k2); SU(0, 64, k2); }
    asm volatile("s_waitcnt lgkmcnt(8)" ::: "memory");
    __builtin_amdgcn_s_barrier(); WAITL0; MM(0); __builtin_amdgcn_s_barrier();

    // ---- ph6: q1; stage k2 B-u2,B-u3,A-u3  [k2 fully issued]
    readA4(Aq, 1);
    if (p2) { SU(1, 128, k2); SU(1, 192, k2); SU(0, 192, k2); }
    __builtin_amdgcn_s_barrier(); WAITL0; MM(2); __builtin_amdgcn_s_barrier();

    // ---- ph7: q2; stage k3 A-u0,A-u2 (Q rows retired at ph6 end)
    readA4(Aq, 2);
    if (p3) { SU(0, 0, k3); SU(0, 128, k3); }
    __builtin_amdgcn_s_barrier(); WAITL0; MM(4); __builtin_amdgcn_s_barrier();

    // ---- ph8: q3; vmcnt(2) proves k2 fully landed (only ph7's pair in flight)
    readA4(Aq, 3);
    __builtin_amdgcn_s_barrier(); WAITL0; MM(6);
    if (p3) asm volatile("s_waitcnt vmcnt(2)" ::: "memory");
    else    asm volatile("s_waitcnt vmcnt(0)" ::: "memory");
    __builtin_amdgcn_s_barrier();
  }

  // epilogue: C/D layout col = lane&15, row = 4*(lane>>4) + j
  #pragma unroll
  for (int mi = 0; mi < 8; ++mi) {
    #pragma unroll
    for (int ni = 0; ni < 4; ++ni) {
      const int grow = bm0 + wm * 128 + mi * 16 + ((lane >> 4) << 2);
      const int gcol = bn0 + wn * 64 + ni * 16 + (lane & 15);
      #pragma unroll
      for (int j = 0; j < 4; ++j)
        out[(size_t)(grow + j) * N_DIM + gcol] = acc[mi][ni][j];
    }
  }
}

// ---------------- fallback: fused kernel (ws too small) ----------------
__global__ __launch_bounds__(256, 2) void wq_gemm(
    const float* __restrict__ x, const int* __restrict__ qweight,
    const int* __restrict__ qzeros, const float* __restrict__ scales,
    float* __restrict__ out) {
  __shared__ uint4 lds4[4096];
  char* lds = (char*)lds4;
  const int t = threadIdx.x;
  const int lane = t & 63;
  const int wid = t >> 6;
  const int bn0 = blockIdx.x * BN;
  const int bm0 = blockIdx.y * BM;
  const int c = t & 15;
  const int r0 = (t >> 4) << 2;
  const int wcol = (bn0 >> 3) + c;
  const int m_off = (wid >> 1) * 64;
  const int n_off = (wid & 1) * 64;
  f32x4 acc[4][4];
  #pragma unroll
  for (int i = 0; i < 4; ++i)
    #pragma unroll
    for (int j = 0; j < 4; ++j)
      #pragma unroll
      for (int k = 0; k < 4; ++k) acc[i][j][k] = 0.0f;
  uint32_t qw_r[4], zq_r;
  f32x4 sc_r[2];
  f32x4 a_rf[4][2];
  auto loadA = [&](int kt) {
    const float* gb = x + (size_t)(bm0 + (t >> 3)) * K_DIM + kt * BK + (t & 7) * 8;
    #pragma unroll
    for (int rr = 0; rr < 4; ++rr) {
      const float* p = gb + (size_t)rr * 32 * K_DIM;
      a_rf[rr][0] = *(const f32x4*)(p);
      a_rf[rr][1] = *(const f32x4*)(p + 4);
    }
  };
  auto writeA = [&](int buf) {
    char* Ab = lds + buf * 16384;
    const int swz = ((t >> 3) & 7) << 4;
    #pragma unroll
    for (int rr = 0; rr < 4; ++rr) {
      uint4 w;
      w.x = pkh(a_rf[rr][0][0], a_rf[rr][0][1]);
      w.y = pkh(a_rf[rr][0][2], a_rf[rr][0][3]);
      w.z = pkh(a_rf[rr][1][0], a_rf[rr][1][1]);
      w.w = pkh(a_rf[rr][1][2], a_rf[rr][1][3]);
      *(uint4*)(Ab + ((rr * 4096 + t * 16) ^ swz)) = w;
    }
  };
  auto issueB = [&](int kt) {
    const int kb = kt * BK + r0;
    const int* qp = qweight + (size_t)kb * NWORDS + wcol;
    qw_r[0] = (uint32_t)qp[0];
    qw_r[1] = (uint32_t)qp[NWORDS];
    qw_r[2] = (uint32_t)qp[2 * NWORDS];
    qw_r[3] = (uint32_t)qp[3 * NWORDS];
    const int g = kt >> 1;
    zq_r = (uint32_t)qzeros[(size_t)g * NWORDS + wcol];
    const float* sp = scales + (size_t)g * N_DIM + bn0 + c * 8;
    sc_r[0] = *(const f32x4*)sp;
    sc_r[1] = *(const f32x4*)(sp + 4);
  };
  auto dequantB = [&](int buf) {
    char* Bb = lds + 32768 + buf * 16384;
    const uint32_t ze = zq_r & 0x0F0F0F0Fu;
    const uint32_t zo = (zq_r >> 4) & 0x0F0F0F0Fu;
    uint32_t e[4], o[4];
    #pragma unroll
    for (int j = 0; j < 4; ++j) {
      e[j] = qw_r[j] & 0x0F0F0F0Fu;
      o[j] = (qw_r[j] >> 4) & 0x0F0F0F0Fu;
    }
    #pragma unroll
    for (int m = 0; m < 4; ++m) {
      const float sf0 = sc_r[(2 * m) >> 2][(2 * m) & 3];
      const float sf1 = sc_r[(2 * m + 1) >> 2][(2 * m + 1) & 3];
      const float cf0 = -ub(ze, m) * sf0;
      const float cf1 = -ub(zo, m) * sf1;
      {
        const float v0 = fmaf(ub(e[0], m), sf0, cf0);
        const float v1 = fmaf(ub(e[1], m), sf0, cf0);
        const float v2 = fmaf(ub(e[2], m), sf0, cf0);
        const float v3 = fmaf(ub(e[3], m), sf0, cf0);
        const int nl = c * 8 + 2 * m;
        int ad = (nl << 7) + (r0 << 1);
        ad ^= ((((nl >> 3) ^ nl) & 7) << 4);
        uint2 p; p.x = pkh(v0, v1); p.y = pkh(v2, v3);
        *(uint2*)(Bb + ad) = p;
      }
      {
        const float v0 = fmaf(ub(o[0], m), sf1, cf1);
        const float v1 = fmaf(ub(o[1], m), sf1, cf1);
        const float v2 = fmaf(ub(o[2], m), sf1, cf1);
        const float v3 = fmaf(ub(o[3], m), sf1, cf1);
        const int nl = c * 8 + 2 * m + 1;
        int ad = (nl << 7) + (r0 << 1);
        ad ^= ((((nl >> 3) ^ nl) & 7) << 4);
        uint2 p; p.x = pkh(v0, v1); p.y = pkh(v2, v3);
        *(uint2*)(Bb + ad) = p;
      }
    }
  };
  auto compute = [&](int buf) {
    const char* A = lds + buf * 16384;
    const char* B = lds + 32768 + buf * 16384;
    const int ra = m_off + (lane & 15);
    const int swa = (lane & 7) << 4;
    const int kb0 = (lane >> 4) << 4;
    #pragma unroll
    for (int ks = 0; ks < 2; ++ks) {
      half8 a[4], b[4];
      #pragma unroll
      for (int mi = 0; mi < 4; ++mi) {
        const int ad = ((ra + mi * 16) << 7) + ks * 64 + kb0;
        a[mi] = *(const half8*)(A + (ad ^ swa));
      }
      #pragma unroll
      for (int ni = 0; ni < 4; ++ni) {
        const int nl = n_off + ni * 16 + (lane & 15);
        int ad = (nl << 7) + ks * 64 + kb0;
        ad ^= ((((nl >> 3) ^ nl) & 7) << 4);
        b[ni] = *(const half8*)(B + ad);
      }
      #pragma unroll
      for (int mi = 0; mi < 4; ++mi)
        #pragma unroll
        for (int ni = 0; ni < 4; ++ni)
          acc[mi][ni] = __builtin_amdgcn_mfma_f32_16x16x32_f16(
              a[mi], b[ni], acc[mi][ni], 0, 0, 0);
    }
  };
  loadA(0); issueB(0); writeA(0); dequantB(0);
  __syncthreads();
  int cur = 0;
  for (int kt = 0; kt < NT; ++kt) {
    const int nxt = cur ^ 1;
    if (kt + 1 < NT) { loadA(kt + 1); issueB(kt + 1); }
    compute(cur);
    if (kt + 1 < NT) { writeA(nxt); dequantB(nxt); }
    __syncthreads();
    cur = nxt;
  }
  #pragma unroll
  for (int mi = 0; mi < 4; ++mi) {
    #pragma unroll
    for (int ni = 0; ni < 4; ++ni) {
      const int grow = bm0 + m_off + mi * 16 + ((lane >> 4) << 2);
      const int gcol = bn0 + n_off + ni * 16 + (lane & 15);
      #pragma unroll
      for (int j = 0; j < 4; ++j)
        out[(size_t)(grow + j) * N_DIM + gcol] = acc[mi][ni][j];
    }
  }
}

extern "C" void kernel_launch(void* const* d_in, const int* in_sizes, int n_in,
                              void* d_out, int out_size, void* d_ws, size_t ws_size,
                              hipStream_t stream) {
  const float* x = (const float*)d_in[0];
  const int* qw = (const int*)d_in[1];
  const int* qz = (const int*)d_in[2];
  const float* sc = (const float*)d_in[3];
  float* out = (float*)d_out;

  const size_t XH_BYTES = (size_t)M_DIM * K_DIM * 2;   // 67,108,864
  const size_t WT_BYTES = (size_t)N_DIM * K_DIM * 2;   // 90,177,536

  if (ws_size >= XH_BYTES + WT_BYTES) {
    __fp16* xh = (__fp16*)d_ws;
    __fp16* wt = (__fp16*)((char*)d_ws + XH_BYTES);
    prep<<<dim3(XBLK + NWORDS * 16), dim3(256), 0, stream>>>(x, qw, qz, sc, xh, wt);
    gemm_f16_256<<<dim3((M_DIM / 256) * (N_DIM / 256)), dim3(512), 0, stream>>>(xh, wt, out);
  } else {
    wq_gemm<<<dim3(N_DIM / BN, M_DIM / BM), dim3(256), 0, stream>>>(x, qw, qz, sc, out);
  }
}

// Round 17
// 773.459 us; speedup vs baseline: 1.0437x; 1.0437x over previous
//
#include <hip/hip_runtime.h>
#include <hip/hip_bf16.h>
#include <stdint.h>

#define M_DIM 8192
#define K_DIM 4096
#define N_DIM 11008
#define NWORDS (N_DIM / 8)   // 1376
#define BM 128
#define BN 128
#define BK 64
#define NT (K_DIM / BK)      // 64

typedef _Float16 half8 __attribute__((ext_vector_type(8)));  // 8 x f16 (4 VGPRs)
typedef __fp16 fp16x2 __attribute__((ext_vector_type(2)));
typedef __attribute__((ext_vector_type(4))) float f32x4;

typedef const __attribute__((address_space(1))) uint32_t glb_u32;
typedef __attribute__((address_space(3))) uint32_t lds_u32;

__device__ __forceinline__ uint32_t pkh(float lo, float hi) {
  union { fp16x2 h; uint32_t u; } cv;
  cv.h = __builtin_amdgcn_cvt_pkrtz(lo, hi);
  return cv.u;
}

__device__ __forceinline__ float ub(uint32_t v, int b) {
  return (float)((v >> (8 * b)) & 0xFFu);
}

// ---------------- fused pre-pass: blocks [0,16384) convert x; rest dequant W ----------------
#define XBLK 16384   // (M*K)/(256*8)
__global__ __launch_bounds__(256) void prep(const float* __restrict__ x,
                                            const int* __restrict__ qweight,
                                            const int* __restrict__ qzeros,
                                            const float* __restrict__ scales,
                                            __fp16* __restrict__ xh,
                                            __fp16* __restrict__ wt) {
  if (blockIdx.x < XBLK) {
    const size_t i8 = ((size_t)blockIdx.x * 256 + threadIdx.x) * 8;
    f32x4 v0 = *(const f32x4*)(x + i8);
    f32x4 v1 = *(const f32x4*)(x + i8 + 4);
    uint4 w;
    w.x = pkh(v0[0], v0[1]); w.y = pkh(v0[2], v0[3]);
    w.z = pkh(v1[0], v1[1]); w.w = pkh(v1[2], v1[3]);
    *(uint4*)(xh + i8) = w;
  } else {
    const int b2 = blockIdx.x - XBLK;
    const int c = b2 >> 4;                    // word column 0..1375 (8 n's)
    const int k = (b2 & 15) * 256 + threadIdx.x;
    const uint32_t q = (uint32_t)qweight[(size_t)k * NWORDS + c];
    const int g = k >> 7;                     // G=128
    const uint32_t z = (uint32_t)qzeros[(size_t)g * NWORDS + c];
    const float* sp = scales + (size_t)g * N_DIM + c * 8;
    const f32x4 s0 = *(const f32x4*)sp;
    const f32x4 s1 = *(const f32x4*)(sp + 4);
    #pragma unroll
    for (int j = 0; j < 8; ++j) {
      const int qv = (int)((q >> (4 * j)) & 15u);
      const int zv = (int)((z >> (4 * j)) & 15u);
      const float sj = (j < 4) ? s0[j & 3] : s1[j & 3];
      const float v = (float)(qv - zv) * sj;
      wt[(size_t)(c * 8 + j) * K_DIM + k] = (__fp16)v;   // coalesced over k (lane)
    }
  }
}

// ---------------- main GEMM: 256x256, BK=64, 4-subphase never-drain (best: r8) ----------------
// LDS: buf0 @0, buf1 @65536; within buf: A 256x128B @0 (32KB), B 256x128B @32768.
// Storage swizzle: (row r, byte c in [0,128)) at  r*128 + (c ^ ((r&7)<<4)).
// Stage unit = 64 rows x 128B = 8KB = 1 load/thread. Per K-tile 8 units, issue
// order B0,B1|B2,B3|A0,A2|A1,A3 (2/phase). Invariant entering tile t: t's
// B*,A0,A2 landed; A1,A3 (2 loads) in flight -> mid vmcnt(4), boundary vmcnt(2).
__global__ __launch_bounds__(512, 2) void gemm_f16_256(
    const __fp16* __restrict__ xh,        // [M,K] fp16
    const __fp16* __restrict__ wt,        // [N,K] fp16
    float* __restrict__ out) {            // [M,N] fp32
  __shared__ uint4 lds4[8192];            // 128 KiB
  char* lds = (char*)lds4;

  const int t = threadIdx.x;
  const int lane = t & 63;
  const int wid = t >> 6;        // 0..7
  const int wm = wid >> 2;       // 0..1  (M half)
  const int wn = wid & 3;        // 0..3  (N quarter)

  // XCD-aware bijective swizzle: 1376 blocks = 8 XCD chunks x 172
  const int flat = blockIdx.x;
  const int swz = (flat & 7) * 172 + (flat >> 3);
  const int bm0 = (swz & 31) * 256;   // M fastest within chunk -> B panel L2-resident
  const int bn0 = (swz >> 5) * 256;

  f32x4 acc[8][4];
  #pragma unroll
  for (int i = 0; i < 8; ++i)
    #pragma unroll
    for (int j = 0; j < 4; ++j)
      #pragma unroll
      for (int k = 0; k < 4; ++k) acc[i][j][k] = 0.0f;

  // ---- staging constants. Thread t covers storage byte rb*128 + t*16 of a unit.
  const int sr = t >> 3;                              // storage row within unit
  const int cb = (((t & 7) ^ (sr & 7)) << 4);         // inverse-swizzled source col
  const char* gA = (const char*)xh + (size_t)(bm0 + sr) * (K_DIM * 2) + cb;
  const char* gB = (const char*)wt + (size_t)(bn0 + sr) * (K_DIM * 2) + cb;
  const int ldst = wid * 1024;                        // wave-uniform; HW adds lane*16

  auto SU = [&](int isB, int rb, int kt1, int wb) {   // stage one 8KB unit
    const char* g = (isB ? gB : gA) + (size_t)rb * (K_DIM * 2) + (size_t)kt1 * 128;
    __builtin_amdgcn_global_load_lds(
        (glb_u32*)g,
        (lds_u32*)(lds + wb + (isB ? 32768 : 0) + rb * 128 + ldst), 16, 0, 0);
  };

  // ---- read-side constants
  const int swr = (lane & 7) << 4;
  const int q16 = (lane >> 4) << 4;
  const int fr = lane & 15;

  // prologue: tile 0 -> buf0 (order leaves A-u1,A-u3 in flight after vmcnt(2))
  SU(1, 0, 0, 0); SU(1, 64, 0, 0); SU(1, 128, 0, 0); SU(1, 192, 0, 0);
  SU(0, 0, 0, 0); SU(0, 128, 0, 0); SU(0, 64, 0, 0); SU(0, 192, 0, 0);
  asm volatile("s_waitcnt vmcnt(2)" ::: "memory");
  __builtin_amdgcn_s_barrier();

  for (int kt = 0; kt < NT; ++kt) {
    const int rbuf = (kt & 1) << 16;
    const int wbuf = rbuf ^ 65536;
    const char* A = lds + rbuf + wm * 16384;
    const char* B = lds + rbuf + 32768 + wn * 8192;
    const bool pf = (kt + 1 < NT);

    half8 b[4][2];

    // ---- PHASE 0: stage B-u0,B-u1; read all b-frags + a(0,1); 16 MFMA
    if (pf) { SU(1, 0, kt + 1, wbuf); SU(1, 64, kt + 1, wbuf); }
    #pragma unroll
    for (int ni = 0; ni < 4; ++ni)
      #pragma unroll
      for (int ks = 0; ks < 2; ++ks)
        b[ni][ks] = *(const half8*)(B + ((((ni * 16 + fr) << 7) + ks * 64 + q16) ^ swr));
    {
      half8 a[2][2];
      #pragma unroll
      for (int m2 = 0; m2 < 2; ++m2)
        #pragma unroll
        for (int ks = 0; ks < 2; ++ks)
          a[m2][ks] = *(const half8*)(A + (((((0 + m2) * 16 + fr) << 7) + ks * 64 + q16) ^ swr));
      __builtin_amdgcn_s_setprio(1);
      #pragma unroll
      for (int m2 = 0; m2 < 2; ++m2)
        #pragma unroll
        for (int ni = 0; ni < 4; ++ni)
          #pragma unroll
          for (int ks = 0; ks < 2; ++ks)
            acc[0 + m2][ni] = __builtin_amdgcn_mfma_f32_16x16x32_f16(
                a[m2][ks], b[ni][ks], acc[0 + m2][ni], 0, 0, 0);
      __builtin_amdgcn_s_setprio(0);
    }

    // ---- PHASE 1: stage B-u2,B-u3; a(2,3); 16 MFMA
    if (pf) { SU(1, 128, kt + 1, wbuf); SU(1, 192, kt + 1, wbuf); }
    {
      half8 a[2][2];
      #pragma unroll
      for (int m2 = 0; m2 < 2; ++m2)
        #pragma unroll
        for (int ks = 0; ks < 2; ++ks)
          a[m2][ks] = *(const half8*)(A + (((((2 + m2) * 16 + fr) << 7) + ks * 64 + q16) ^ swr));
      __builtin_amdgcn_s_setprio(1);
      #pragma unroll
      for (int m2 = 0; m2 < 2; ++m2)
        #pragma unroll
        for (int ni = 0; ni < 4; ++ni)
          #pragma unroll
          for (int ks = 0; ks < 2; ++ks)
            acc[2 + m2][ni] = __builtin_amdgcn_mfma_f32_16x16x32_f16(
                a[m2][ks], b[ni][ks], acc[2 + m2][ni], 0, 0, 0);
      __builtin_amdgcn_s_setprio(0);
    }

    // ---- MID: this tile's A-u1,A-u3 must be landed before phases 2-3 read them
    if (pf) asm volatile("s_waitcnt vmcnt(4)" ::: "memory");
    else    asm volatile("s_waitcnt vmcnt(0)" ::: "memory");
    __builtin_amdgcn_s_barrier();

    // ---- PHASE 2: stage A-u0(rows0-63),A-u2(rows128-191); a(4,5); 16 MFMA
    if (pf) { SU(0, 0, kt + 1, wbuf); SU(0, 128, kt + 1, wbuf); }
    {
      half8 a[2][2];
      #pragma unroll
      for (int m2 = 0; m2 < 2; ++m2)
        #pragma unroll
        for (int ks = 0; ks < 2; ++ks)
          a[m2][ks] = *(const half8*)(A + (((((4 + m2) * 16 + fr) << 7) + ks * 64 + q16) ^ swr));
      __builtin_amdgcn_s_setprio(1);
      #pragma unroll
      for (int m2 = 0; m2 < 2; ++m2)
        #pragma unroll
        for (int ni = 0; ni < 4; ++ni)
          #pragma unroll
          for (int ks = 0; ks < 2; ++ks)
            acc[4 + m2][ni] = __builtin_amdgcn_mfma_f32_16x16x32_f16(
                a[m2][ks], b[ni][ks], acc[4 + m2][ni], 0, 0, 0);
      __builtin_amdgcn_s_setprio(0);
    }

    // ---- PHASE 3: stage A-u1(rows64-127),A-u3(rows192-255); a(6,7); 16 MFMA
    if (pf) { SU(0, 64, kt + 1, wbuf); SU(0, 192, kt + 1, wbuf); }
    {
      half8 a[2][2];
      #pragma unroll
      for (int m2 = 0; m2 < 2; ++m2)
        #pragma unroll
        for (int ks = 0; ks < 2; ++ks)
          a[m2][ks] = *(const half8*)(A + (((((6 + m2) * 16 + fr) << 7) + ks * 64 + q16) ^ swr));
      __builtin_amdgcn_s_setprio(1);
      #pragma unroll
      for (int m2 = 0; m2 < 2; ++m2)
        #pragma unroll
        for (int ni = 0; ni < 4; ++ni)
          #pragma unroll
          for (int ks = 0; ks < 2; ++ks)
            acc[6 + m2][ni] = __builtin_amdgcn_mfma_f32_16x16x32_f16(
                a[m2][ks], b[ni][ks], acc[6 + m2][ni], 0, 0, 0);
      __builtin_amdgcn_s_setprio(0);
    }

    // ---- BOUNDARY: next tile's B*,A-u0,A-u2 landed; its A-u1,A-u3 stay in flight
    asm volatile("s_waitcnt vmcnt(2)" ::: "memory");
    __builtin_amdgcn_s_barrier();
  }

  // epilogue: C/D layout col = lane&15, row = 4*(lane>>4) + j
  // nontemporal: C is streaming; keep B panels resident in L2
  #pragma unroll
  for (int mi = 0; mi < 8; ++mi) {
    #pragma unroll
    for (int ni = 0; ni < 4; ++ni) {
      const int grow = bm0 + wm * 128 + mi * 16 + ((lane >> 4) << 2);
      const int gcol = bn0 + wn * 64 + ni * 16 + (lane & 15);
      #pragma unroll
      for (int j = 0; j < 4; ++j)
        __builtin_nontemporal_store(acc[mi][ni][j],
                                    &out[(size_t)(grow + j) * N_DIM + gcol]);
    }
  }
}

// ---------------- fallback: fused kernel (ws too small) ----------------
__global__ __launch_bounds__(256, 2) void wq_gemm(
    const float* __restrict__ x, const int* __restrict__ qweight,
    const int* __restrict__ qzeros, const float* __restrict__ scales,
    float* __restrict__ out) {
  __shared__ uint4 lds4[4096];
  char* lds = (char*)lds4;
  const int t = threadIdx.x;
  const int lane = t & 63;
  const int wid = t >> 6;
  const int bn0 = blockIdx.x * BN;
  const int bm0 = blockIdx.y * BM;
  const int c = t & 15;
  const int r0 = (t >> 4) << 2;
  const int wcol = (bn0 >> 3) + c;
  const int m_off = (wid >> 1) * 64;
  const int n_off = (wid & 1) * 64;
  f32x4 acc[4][4];
  #pragma unroll
  for (int i = 0; i < 4; ++i)
    #pragma unroll
    for (int j = 0; j < 4; ++j)
      #pragma unroll
      for (int k = 0; k < 4; ++k) acc[i][j][k] = 0.0f;
  uint32_t qw_r[4], zq_r;
  f32x4 sc_r[2];
  f32x4 a_rf[4][2];
  auto loadA = [&](int kt) {
    const float* gb = x + (size_t)(bm0 + (t >> 3)) * K_DIM + kt * BK + (t & 7) * 8;
    #pragma unroll
    for (int rr = 0; rr < 4; ++rr) {
      const float* p = gb + (size_t)rr * 32 * K_DIM;
      a_rf[rr][0] = *(const f32x4*)(p);
      a_rf[rr][1] = *(const f32x4*)(p + 4);
    }
  };
  auto writeA = [&](int buf) {
    char* Ab = lds + buf * 16384;
    const int swz = ((t >> 3) & 7) << 4;
    #pragma unroll
    for (int rr = 0; rr < 4; ++rr) {
      uint4 w;
      w.x = pkh(a_rf[rr][0][0], a_rf[rr][0][1]);
      w.y = pkh(a_rf[rr][0][2], a_rf[rr][0][3]);
      w.z = pkh(a_rf[rr][1][0], a_rf[rr][1][1]);
      w.w = pkh(a_rf[rr][1][2], a_rf[rr][1][3]);
      *(uint4*)(Ab + ((rr * 4096 + t * 16) ^ swz)) = w;
    }
  };
  auto issueB = [&](int kt) {
    const int kb = kt * BK + r0;
    const int* qp = qweight + (size_t)kb * NWORDS + wcol;
    qw_r[0] = (uint32_t)qp[0];
    qw_r[1] = (uint32_t)qp[NWORDS];
    qw_r[2] = (uint32_t)qp[2 * NWORDS];
    qw_r[3] = (uint32_t)qp[3 * NWORDS];
    const int g = kt >> 1;
    zq_r = (uint32_t)qzeros[(size_t)g * NWORDS + wcol];
    const float* sp = scales + (size_t)g * N_DIM + bn0 + c * 8;
    sc_r[0] = *(const f32x4*)sp;
    sc_r[1] = *(const f32x4*)(sp + 4);
  };
  auto dequantB = [&](int buf) {
    char* Bb = lds + 32768 + buf * 16384;
    const uint32_t ze = zq_r & 0x0F0F0F0Fu;
    const uint32_t zo = (zq_r >> 4) & 0x0F0F0F0Fu;
    uint32_t e[4], o[4];
    #pragma unroll
    for (int j = 0; j < 4; ++j) {
      e[j] = qw_r[j] & 0x0F0F0F0Fu;
      o[j] = (qw_r[j] >> 4) & 0x0F0F0F0Fu;
    }
    #pragma unroll
    for (int m = 0; m < 4; ++m) {
      const float sf0 = sc_r[(2 * m) >> 2][(2 * m) & 3];
      const float sf1 = sc_r[(2 * m + 1) >> 2][(2 * m + 1) & 3];
      const float cf0 = -ub(ze, m) * sf0;
      const float cf1 = -ub(zo, m) * sf1;
      {
        const float v0 = fmaf(ub(e[0], m), sf0, cf0);
        const float v1 = fmaf(ub(e[1], m), sf0, cf0);
        const float v2 = fmaf(ub(e[2], m), sf0, cf0);
        const float v3 = fmaf(ub(e[3], m), sf0, cf0);
        const int nl = c * 8 + 2 * m;
        int ad = (nl << 7) + (r0 << 1);
        ad ^= ((((nl >> 3) ^ nl) & 7) << 4);
        uint2 p; p.x = pkh(v0, v1); p.y = pkh(v2, v3);
        *(uint2*)(Bb + ad) = p;
      }
      {
        const float v0 = fmaf(ub(o[0], m), sf1, cf1);
        const float v1 = fmaf(ub(o[1], m), sf1, cf1);
        const float v2 = fmaf(ub(o[2], m), sf1, cf1);
        const float v3 = fmaf(ub(o[3], m), sf1, cf1);
        const int nl = c * 8 + 2 * m + 1;
        int ad = (nl << 7) + (r0 << 1);
        ad ^= ((((nl >> 3) ^ nl) & 7) << 4);
        uint2 p; p.x = pkh(v0, v1); p.y = pkh(v2, v3);
        *(uint2*)(Bb + ad) = p;
      }
    }
  };
  auto compute = [&](int buf) {
    const char* A = lds + buf * 16384;
    const char* B = lds + 32768 + buf * 16384;
    const int ra = m_off + (lane & 15);
    const int swa = (lane & 7) << 4;
    const int kb0 = (lane >> 4) << 4;
    #pragma unroll
    for (int ks = 0; ks < 2; ++ks) {
      half8 a[4], b[4];
      #pragma unroll
      for (int mi = 0; mi < 4; ++mi) {
        const int ad = ((ra + mi * 16) << 7) + ks * 64 + kb0;
        a[mi] = *(const half8*)(A + (ad ^ swa));
      }
      #pragma unroll
      for (int ni = 0; ni < 4; ++ni) {
        const int nl = n_off + ni * 16 + (lane & 15);
        int ad = (nl << 7) + ks * 64 + kb0;
        ad ^= ((((nl >> 3) ^ nl) & 7) << 4);
        b[ni] = *(const half8*)(B + ad);
      }
      #pragma unroll
      for (int mi = 0; mi < 4; ++mi)
        #pragma unroll
        for (int ni = 0; ni < 4; ++ni)
          acc[mi][ni] = __builtin_amdgcn_mfma_f32_16x16x32_f16(
              a[mi], b[ni], acc[mi][ni], 0, 0, 0);
    }
  };
  loadA(0); issueB(0); writeA(0); dequantB(0);
  __syncthreads();
  int cur = 0;
  for (int kt = 0; kt < NT; ++kt) {
    const int nxt = cur ^ 1;
    if (kt + 1 < NT) { loadA(kt + 1); issueB(kt + 1); }
    compute(cur);
    if (kt + 1 < NT) { writeA(nxt); dequantB(nxt); }
    __syncthreads();
    cur = nxt;
  }
  #pragma unroll
  for (int mi = 0; mi < 4; ++mi) {
    #pragma unroll
    for (int ni = 0; ni < 4; ++ni) {
      const int grow = bm0 + m_off + mi * 16 + ((lane >> 4) << 2);
      const int gcol = bn0 + n_off + ni * 16 + (lane & 15);
      #pragma unroll
      for (int j = 0; j < 4; ++j)
        out[(size_t)(grow + j) * N_DIM + gcol] = acc[mi][ni][j];
    }
  }
}

extern "C" void kernel_launch(void* const* d_in, const int* in_sizes, int n_in,
                              void* d_out, int out_size, void* d_ws, size_t ws_size,
                              hipStream_t stream) {
  const float* x = (const float*)d_in[0];
  const int* qw = (const int*)d_in[1];
  const int* qz = (const int*)d_in[2];
  const float* sc = (const float*)d_in[3];
  float* out = (float*)d_out;

  const size_t XH_BYTES = (size_t)M_DIM * K_DIM * 2;   // 67,108,864
  const size_t WT_BYTES = (size_t)N_DIM * K_DIM * 2;   // 90,177,536

  if (ws_size >= XH_BYTES + WT_BYTES) {
    __fp16* xh = (__fp16*)d_ws;
    __fp16* wt = (__fp16*)((char*)d_ws + XH_BYTES);
    prep<<<dim3(XBLK + NWORDS * 16), dim3(256), 0, stream>>>(x, qw, qz, sc, xh, wt);
    gemm_f16_256<<<dim3((M_DIM / 256) * (N_DIM / 256)), dim3(512), 0, stream>>>(xh, wt, out);
  } else {
    wq_gemm<<<dim3(N_DIM / BN, M_DIM / BM), dim3(256), 0, stream>>>(x, qw, qz, sc, out);
  }
}